// Round 2
// baseline (372.605 us; speedup 1.0000x reference)
//
#include <hip/hip_runtime.h>

// Problem: B=4, M_IN=16, M_OUT=32, C=32
// x: (B, M_IN, C, C, C, C) fp32, 256 MiB.
// out[b,n,i,c] = sum_m s_i[b,m,c] * W[m,n],  W = alpha+beta+gamma+delta
//   s_0 = s_1 = x.sum(axes 3,4,5)  (keeps c2)
//   s_2       = x.sum(axes 2,4,5)  (keeps c3)
//   s_3       = x.sum(axes 2,3,5)  (keeps c4)
//
// Two kernels, atomic-free:
//   reduce_k  (2048 blocks): per-block partials into ws
//       s3part[bid][c3]  (bid = (b*16+m)*32 + c2)
//       s4part[bid][c4]
//   finalize_k (4 blocks, one per b): folds partials over c2, derives
//       s1[b,m,c2] = sum_c3 s3part[bm*32+c2][c3], applies W, writes out.
//
// ws layout (floats): s3part[2048*32] | s4part[2048*32]   (512 KB total)

__global__ __launch_bounds__(256) void reduce_k(const float* __restrict__ x,
                                                float* __restrict__ s3part,
                                                float* __restrict__ s4part) {
    const int t   = threadIdx.x;          // 0..255
    const int bid = blockIdx.x;           // (b*16+m)*32 + c2
    const int wv  = t >> 6;               // wave 0..3
    const int g   = (t & 63) >> 3;        // 8-lane group within wave, 0..7

    // lds3[it][slot]: per-iteration (== c3) per-8-lane-group partial sums.
    // 33-stride pad -> conflict-free column reads in the end phase.
    __shared__ float lds3[32][33];

    // Contiguous 128 KiB slab for this (b,m,c2): 8192 float4s.
    const float4* xv = (const float4*)x + (size_t)bid * 8192;

    float acc4 = 0.0f;                    // s4 partial for c4 = t>>3
    #pragma unroll 4
    for (int it = 0; it < 32; ++it) {     // it == c3 (block-uniform)
        float4 v = xv[it * 256 + t];      // block reads contiguous 4 KiB
        float s = (v.x + v.y) + (v.z + v.w);   // sum over 4 consecutive c5
        // butterfly within 8 lanes (same c4): pure ds_swizzle, no cross-32
        s += __shfl_xor(s, 1, 64);
        s += __shfl_xor(s, 2, 64);
        s += __shfl_xor(s, 4, 64);
        // every lane in the 8-group now holds the group sum (c3=it, c4=t>>3)
        acc4 += s;
        if ((t & 7) == 0) lds3[it][wv * 8 + g] = s;
    }

    // s4part: one writer per c4 (group leader), plain store
    if ((t & 7) == 0) s4part[bid * 32 + (t >> 3)] = acc4;

    __syncthreads();

    // s3part[bid][c3] = sum of the 32 group partials for that c3
    if (t < 32) {
        float a = 0.0f;
        #pragma unroll
        for (int k = 0; k < 32; ++k) a += lds3[t][k];   // banks (t+k)%32: clean
        s3part[bid * 32 + t] = a;
    }
}

__global__ __launch_bounds__(256) void finalize_k(const float* __restrict__ s3part,
                                                  const float* __restrict__ s4part,
                                                  const float* __restrict__ alpha,
                                                  const float* __restrict__ beta,
                                                  const float* __restrict__ gamma,
                                                  const float* __restrict__ delta,
                                                  float* __restrict__ out) {
    const int b = blockIdx.x;             // 0..3
    const int t = threadIdx.x;            // 0..255

    __shared__ float S1[16][32];          // s1[m][c2]
    __shared__ float S3[16][32];          // s3[m][c3]
    __shared__ float S4[16][32];          // s4[m][c4]
    __shared__ float W[16][32];           // alpha+beta+gamma+delta

    #pragma unroll
    for (int i = t; i < 512; i += 256)
        W[i >> 5][i & 31] = alpha[i] + beta[i] + gamma[i] + delta[i];

    #pragma unroll
    for (int idx = t; idx < 512; idx += 256) {
        const int m = idx >> 5;
        const int c = idx & 31;
        const int bm = b * 16 + m;
        // s3/s4: fold partials over c2
        float a3 = 0.0f, a4 = 0.0f;
        #pragma unroll 4
        for (int c2 = 0; c2 < 32; ++c2) {
            a3 += s3part[(bm * 32 + c2) * 32 + c];
            a4 += s4part[(bm * 32 + c2) * 32 + c];
        }
        S3[m][c] = a3;
        S4[m][c] = a4;
        // s1[m][c2=c]: sum one s3part row over c3
        float a1 = 0.0f;
        #pragma unroll 4
        for (int k = 0; k < 32; ++k)
            a1 += s3part[(bm * 32 + c) * 32 + k];
        S1[m][c] = a1;
    }
    __syncthreads();

    // out[b,n,i,c], 4096 entries per block, 16 per thread
    #pragma unroll
    for (int idx = t; idx < 4096; idx += 256) {
        const int c = idx & 31;
        const int i = (idx >> 5) & 3;
        const int n = idx >> 7;
        const float (*S)[32] = (i <= 1) ? S1 : (i == 2 ? S3 : S4);
        float acc = 0.0f;
        #pragma unroll
        for (int m = 0; m < 16; ++m)
            acc += S[m][c] * W[m][n];
        out[((b * 32 + n) * 4 + i) * 32 + c] = acc;
    }
}

extern "C" void kernel_launch(void* const* d_in, const int* in_sizes, int n_in,
                              void* d_out, int out_size, void* d_ws, size_t ws_size,
                              hipStream_t stream) {
    const float* x     = (const float*)d_in[0];
    const float* alpha = (const float*)d_in[1];
    const float* beta  = (const float*)d_in[2];
    const float* gamma = (const float*)d_in[3];
    const float* delta = (const float*)d_in[4];
    float* out = (float*)d_out;
    float* ws  = (float*)d_ws;

    float* s3part = ws;            // 65536 floats
    float* s4part = ws + 65536;    // 65536 floats

    reduce_k<<<2048, 256, 0, stream>>>(x, s3part, s4part);
    finalize_k<<<4, 256, 0, stream>>>(s3part, s4part, alpha, beta, gamma, delta, out);
}

// Round 3
// 371.111 us; speedup vs baseline: 1.0040x; 1.0040x over previous
//
#include <hip/hip_runtime.h>

// Problem: B=4, M_IN=16, M_OUT=32, C=32
// x: (B, M_IN, C, C, C, C) fp32, 256 MiB.
// out[b,n,i,c] = sum_m s_i[b,m,c] * W[m,n],  W = alpha+beta+gamma+delta
//   s_0 = s_1 = x.sum(axes 3,4,5)  (keeps c2)
//   s_2       = x.sum(axes 2,4,5)  (keeps c3)
//   s_3       = x.sum(axes 2,3,5)  (keeps c4)
//
// reduce_k (2048 blocks, one per (b,m,c2) slab of 128 KiB):
//   hot loop = load dwordx4 + 4 adds + 1 conflict-free ds_write_b32. All
//   cross-lane reduction deferred to a post-loop phase.
//   Outputs: s1[bid] (exact, exclusive store), s3part[bid][c3],
//            s4part[bid][c4] (per-block partials, plain stores, no atomics).
// finalize_k (4 blocks): folds partials over c2, applies W, writes out.
//
// ws layout (floats): s3part[65536] | s4part[65536] | s1[2048]

__global__ __launch_bounds__(256) void reduce_k(const float* __restrict__ x,
                                                float* __restrict__ s3part,
                                                float* __restrict__ s4part,
                                                float* __restrict__ s1) {
    const int t   = threadIdx.x;          // 0..255
    const int bid = blockIdx.x;           // (b*16+m)*32 + c2

    __shared__ float l3[256][33];         // raw per-thread s, row=t col=it (33: pad)
    __shared__ float red3[8][32];
    __shared__ float lds1[4];

    // Contiguous 128 KiB slab for this (b,m,c2): 8192 float4s.
    const float4* xv = (const float4*)x + (size_t)bid * 8192;

    float acc = 0.0f;                     // per-thread total (c4 = t>>3 fixed)
    #pragma unroll 8
    for (int it = 0; it < 32; ++it) {     // it == c3 (block-uniform)
        float4 v = xv[it * 256 + t];      // block reads contiguous 4 KiB
        float s = (v.x + v.y) + (v.z + v.w);
        acc += s;
        l3[t][it] = s;                    // bank (t+it)%32: 2-way, free
    }

    // s4: the 8 lanes t..t|7 share c4 = t>>3
    float g = acc;
    g += __shfl_xor(g, 1, 64);
    g += __shfl_xor(g, 2, 64);
    g += __shfl_xor(g, 4, 64);
    if ((t & 7) == 0) s4part[bid * 32 + (t >> 3)] = g;

    // s1: continue to full-wave total, then combine 4 waves via LDS
    float w = g;
    w += __shfl_xor(w, 8, 64);
    w += __shfl_xor(w, 16, 64);
    w += __shfl_xor(w, 32, 64);
    if ((t & 63) == 0) lds1[t >> 6] = w;

    __syncthreads();

    // s3: fold the 256 raw rows for each c3
    {
        const int it = t & 31;            // c3 this thread folds
        const int p  = t >> 5;            // which 32-row chunk
        float a = 0.0f;
        #pragma unroll
        for (int k = 0; k < 32; ++k)
            a += l3[p * 32 + k][it];      // bank (k+it)%32: 2-way, free
        red3[p][it] = a;
    }
    if (t == 0)
        s1[bid] = (lds1[0] + lds1[1]) + (lds1[2] + lds1[3]);  // exact, exclusive

    __syncthreads();

    if (t < 32) {
        float a = ((red3[0][t] + red3[1][t]) + (red3[2][t] + red3[3][t]))
                + ((red3[4][t] + red3[5][t]) + (red3[6][t] + red3[7][t]));
        s3part[bid * 32 + t] = a;
    }
}

__global__ __launch_bounds__(256) void finalize_k(const float* __restrict__ s3part,
                                                  const float* __restrict__ s4part,
                                                  const float* __restrict__ s1,
                                                  const float* __restrict__ alpha,
                                                  const float* __restrict__ beta,
                                                  const float* __restrict__ gamma,
                                                  const float* __restrict__ delta,
                                                  float* __restrict__ out) {
    const int b = blockIdx.x;             // 0..3
    const int t = threadIdx.x;            // 0..255

    __shared__ float S[3][16][32];        // S[0]=s1[m][c2] S[1]=s3[m][c3] S[2]=s4[m][c4]
    __shared__ float W[512];              // alpha+beta+gamma+delta, [m*32+n]

    #pragma unroll
    for (int i = t; i < 512; i += 256)
        W[i] = (alpha[i] + beta[i]) + (gamma[i] + delta[i]);

    #pragma unroll
    for (int idx = t; idx < 512; idx += 256) {
        const int m = idx >> 5;
        const int c = idx & 31;
        const int bm = b * 16 + m;
        S[0][m][c] = s1[bm * 32 + c];     // exact already
        float a3 = 0.0f, a4 = 0.0f;
        #pragma unroll 4
        for (int c2 = 0; c2 < 32; ++c2) { // coalesced across lanes (c adjacent)
            a3 += s3part[(bm * 32 + c2) * 32 + c];
            a4 += s4part[(bm * 32 + c2) * 32 + c];
        }
        S[1][m][c] = a3;
        S[2][m][c] = a4;
    }
    __syncthreads();

    // out[b,n,i,c]: 4096 per block, 16 per thread
    #pragma unroll
    for (int idx = t; idx < 4096; idx += 256) {
        const int c = idx & 31;
        const int i = (idx >> 5) & 3;
        const int n = idx >> 7;
        const float (*Sp)[32] = (i <= 1) ? S[0] : (i == 2 ? S[1] : S[2]);
        float acc = 0.0f;
        #pragma unroll
        for (int m = 0; m < 16; ++m)
            acc += Sp[m][c] * W[m * 32 + n];
        out[((b * 32 + n) * 4 + i) * 32 + c] = acc;
    }
}

extern "C" void kernel_launch(void* const* d_in, const int* in_sizes, int n_in,
                              void* d_out, int out_size, void* d_ws, size_t ws_size,
                              hipStream_t stream) {
    const float* x     = (const float*)d_in[0];
    const float* alpha = (const float*)d_in[1];
    const float* beta  = (const float*)d_in[2];
    const float* gamma = (const float*)d_in[3];
    const float* delta = (const float*)d_in[4];
    float* out = (float*)d_out;
    float* ws  = (float*)d_ws;

    float* s3part = ws;                    // 65536 floats
    float* s4part = ws + 65536;            // 65536 floats
    float* s1v    = ws + 131072;           // 2048 floats

    reduce_k<<<2048, 256, 0, stream>>>(x, s3part, s4part, s1v);
    finalize_k<<<4, 256, 0, stream>>>(s3part, s4part, s1v,
                                      alpha, beta, gamma, delta, out);
}